// Round 9
// baseline (2176.858 us; speedup 1.0000x reference)
//
#include <hip/hip_runtime.h>

// ---------------------------------------------------------------------------
// GraphSAGE 2-layer (mean aggr) + linear classifier, fp32, N=100K, D=64, E=16N
// R8: linears = LDS-broadcast GEMM. lane = output feature j; wave owns 8
//  nodes/iter (acc[8], constant indices only -- R7 spilled via pointer/float4
//  arrays, 256 VGPR + 1.6 GB scratch). Weights in LDS [k][j] natural layout:
//  per-k4 reads are lane-stride-1 b32 = 2-way = free. Node rows staged
//  per-wave into LDS via coalesced float4, read back as broadcasts.
//  Per k4: 64 FMA (128 cyc) vs ~100 LDS cyc -> VALU-bound, floor 10.4 us.
//  Aggregate/scatter/scan identical to the 522 us R5 config (8 passes).
// ---------------------------------------------------------------------------

#define SCAN_BS 1024
#define SCATTER_PASSES 8
#define LIN_BLOCKS 768

__global__ void zero_i32_kernel(int* __restrict__ p, int n) {
  int i = blockIdx.x * blockDim.x + threadIdx.x;
  if (i < n) p[i] = 0;
}

__global__ void hist_kernel(const int* __restrict__ dst, int* __restrict__ deg, int ne) {
  int e = blockIdx.x * blockDim.x + threadIdx.x;
  if (e < ne) atomicAdd(&deg[dst[e]], 1);
}

__device__ __forceinline__ int block_scan_inclusive_1024(int v, int* wsums) {
  int lane = threadIdx.x & 63;
  int wid = threadIdx.x >> 6;
  int s = v;
#pragma unroll
  for (int off = 1; off < 64; off <<= 1) {
    int t = __shfl_up(s, off);
    if (lane >= off) s += t;
  }
  if (lane == 63) wsums[wid] = s;
  __syncthreads();
  if (wid == 0) {
    int ws = (lane < 16) ? wsums[lane] : 0;
#pragma unroll
    for (int off = 1; off < 16; off <<= 1) {
      int t = __shfl_up(ws, off);
      if (lane >= off) ws += t;
    }
    if (lane < 16) wsums[lane] = ws;
  }
  __syncthreads();
  if (wid > 0) s += wsums[wid - 1];
  return s;
}

__global__ void __launch_bounds__(SCAN_BS) scan_a_kernel(const int* __restrict__ deg,
                                                         int* __restrict__ local_excl,
                                                         int* __restrict__ bsums, int n) {
  __shared__ int wsums[16];
  int i = blockIdx.x * SCAN_BS + threadIdx.x;
  int v = (i < n) ? deg[i] : 0;
  int inc = block_scan_inclusive_1024(v, wsums);
  if (i < n) local_excl[i] = inc - v;
  if (threadIdx.x == SCAN_BS - 1) bsums[blockIdx.x] = inc;
}

__global__ void __launch_bounds__(SCAN_BS) scan_b_kernel(const int* __restrict__ bsums,
                                                         int* __restrict__ boffs, int nb) {
  __shared__ int wsums[16];
  int v = ((int)threadIdx.x < nb) ? bsums[threadIdx.x] : 0;
  int inc = block_scan_inclusive_1024(v, wsums);
  if ((int)threadIdx.x < nb) boffs[threadIdx.x] = inc - v;
  if ((int)threadIdx.x == nb - 1) boffs[nb] = inc;
}

__global__ void scan_c_kernel(int* __restrict__ row_ptr, int* __restrict__ cursor,
                              const int* __restrict__ boffs, int n, int nb) {
  int i = blockIdx.x * blockDim.x + threadIdx.x;
  if (i < n) {
    int v = row_ptr[i] + boffs[i >> 10];
    row_ptr[i] = v;
    cursor[i] = v;
  }
  if (i == n) row_ptr[n] = boffs[nb];
}

__global__ void scatter_pass_kernel(const int* __restrict__ src, const int* __restrict__ dst,
                                    int* __restrict__ cursor, int* __restrict__ col,
                                    int ne, int lo, int hi) {
  int e = blockIdx.x * blockDim.x + threadIdx.x;
  if (e < ne) {
    int d = dst[e];
    if (d >= lo && d < hi) {
      int pos = atomicAdd(&cursor[d], 1);
      col[pos] = src[e];
    }
  }
}

// one wave per node, one feature per lane; scalarized col reads, 8 gathers in flight
__global__ void __launch_bounds__(256) aggregate_kernel(const float* __restrict__ xin,
                                                        const int* __restrict__ row_ptr,
                                                        const int* __restrict__ col,
                                                        float* __restrict__ outp, int n) {
  int gwave = (blockIdx.x * 256 + threadIdx.x) >> 6;
  int lane = threadIdx.x & 63;
  if (gwave >= n) return;
  int m = __builtin_amdgcn_readfirstlane(gwave);
  int start = row_ptr[m];
  int end = row_ptr[m + 1];
  float a0 = 0.f, a1 = 0.f, a2 = 0.f, a3 = 0.f, a4 = 0.f, a5 = 0.f, a6 = 0.f, a7 = 0.f;
  int e = start;
  for (; e + 8 <= end; e += 8) {
    int c0 = col[e + 0], c1 = col[e + 1], c2 = col[e + 2], c3 = col[e + 3];
    int c4 = col[e + 4], c5 = col[e + 5], c6 = col[e + 6], c7 = col[e + 7];
    a0 += xin[(size_t)c0 * 64 + lane];
    a1 += xin[(size_t)c1 * 64 + lane];
    a2 += xin[(size_t)c2 * 64 + lane];
    a3 += xin[(size_t)c3 * 64 + lane];
    a4 += xin[(size_t)c4 * 64 + lane];
    a5 += xin[(size_t)c5 * 64 + lane];
    a6 += xin[(size_t)c6 * 64 + lane];
    a7 += xin[(size_t)c7 * 64 + lane];
  }
  for (; e < end; ++e) a0 += xin[(size_t)col[e] * 64 + lane];
  float acc = ((a0 + a1) + (a2 + a3)) + ((a4 + a5) + (a6 + a7));
  int d = end - start;
  float inv = 1.0f / (float)((d > 0) ? d : 1);
  outp[(size_t)m * 64 + lane] = acc * inv;
}

// ---- linear layers: LDS-broadcast GEMM -------------------------------------
// Staging macro body shared by both kernels via a device function.

__device__ __forceinline__ void lin_stage_inputs(float (*sInW)[2][64],
                                                 const float* __restrict__ agg,
                                                 const float* __restrict__ xin,
                                                 int m0, int n, int lane) {
#pragma unroll
  for (int t = 0; t < 4; ++t) {
    int f = t * 64 + lane;   // 0..255
    int mat = f >> 7;        // 0: agg, 1: xin
    int rem = f & 127;
    int m = rem >> 4;
    int k4 = rem & 15;
    int row = m0 + m;
    if (row >= n) row = n - 1;
    const float* bp = mat ? xin : agg;
    float4 v = *(const float4*)(bp + (size_t)row * 64 + (k4 << 2));
    *(float4*)&sInW[m][mat][k4 << 2] = v;
  }
}

__global__ void __launch_bounds__(256) lin_relu_kernel(const float* __restrict__ agg,
                                                       const float* __restrict__ xin,
                                                       const float* __restrict__ Wl,
                                                       const float* __restrict__ bias,
                                                       const float* __restrict__ Wr,
                                                       float* __restrict__ outp, int n) {
  __shared__ float sWl[4096];
  __shared__ float sWr[4096];
  __shared__ float sIn[4][8][2][64];  // [wave][m][mat][k] 16 KB
  int tid = threadIdx.x;
  int lane = tid & 63;
  int wv = tid >> 6;
  for (int i = tid; i < 1024; i += 256) {
    ((float4*)sWl)[i] = ((const float4*)Wl)[i];
    ((float4*)sWr)[i] = ((const float4*)Wr)[i];
  }
  __syncthreads();
  float bv = bias[lane];
  int gw = blockIdx.x * 4 + wv;
  int nw = gridDim.x * 4;
  int ngroups = (n + 7) >> 3;
  for (int g = gw; g < ngroups; g += nw) {
    int m0 = g * 8;
    lin_stage_inputs(sIn[wv], agg, xin, m0, n, lane);
    float acc[8];
#pragma unroll
    for (int m = 0; m < 8; ++m) acc[m] = bv;
#pragma unroll
    for (int k4 = 0; k4 < 16; ++k4) {
      float wl0 = sWl[(k4 * 4 + 0) * 64 + lane];
      float wl1 = sWl[(k4 * 4 + 1) * 64 + lane];
      float wl2 = sWl[(k4 * 4 + 2) * 64 + lane];
      float wl3 = sWl[(k4 * 4 + 3) * 64 + lane];
      float wr0 = sWr[(k4 * 4 + 0) * 64 + lane];
      float wr1 = sWr[(k4 * 4 + 1) * 64 + lane];
      float wr2 = sWr[(k4 * 4 + 2) * 64 + lane];
      float wr3 = sWr[(k4 * 4 + 3) * 64 + lane];
#pragma unroll
      for (int m = 0; m < 8; ++m) {
        float4 a4 = *(const float4*)&sIn[wv][m][0][k4 * 4];
        float4 x4 = *(const float4*)&sIn[wv][m][1][k4 * 4];
        acc[m] = fmaf(a4.x, wl0, acc[m]);
        acc[m] = fmaf(a4.y, wl1, acc[m]);
        acc[m] = fmaf(a4.z, wl2, acc[m]);
        acc[m] = fmaf(a4.w, wl3, acc[m]);
        acc[m] = fmaf(x4.x, wr0, acc[m]);
        acc[m] = fmaf(x4.y, wr1, acc[m]);
        acc[m] = fmaf(x4.z, wr2, acc[m]);
        acc[m] = fmaf(x4.w, wr3, acc[m]);
      }
    }
#pragma unroll
    for (int m = 0; m < 8; ++m) {
      int row = m0 + m;
      if (row < n) outp[(size_t)row * 64 + lane] = fmaxf(acc[m], 0.0f);
    }
  }
}

__global__ void __launch_bounds__(256) lin2_cls_kernel(const float* __restrict__ agg,
                                                       const float* __restrict__ hin,
                                                       const float* __restrict__ Wl,
                                                       const float* __restrict__ bias,
                                                       const float* __restrict__ Wr,
                                                       const float* __restrict__ Wc,
                                                       const float* __restrict__ bc,
                                                       float* __restrict__ outp, int n) {
  __shared__ float sWl[4096];
  __shared__ float sWr[4096];
  __shared__ float sIn[4][8][2][64];
  int tid = threadIdx.x;
  int lane = tid & 63;
  int wv = tid >> 6;
  for (int i = tid; i < 1024; i += 256) {
    ((float4*)sWl)[i] = ((const float4*)Wl)[i];
    ((float4*)sWr)[i] = ((const float4*)Wr)[i];
  }
  __syncthreads();
  float bv = bias[lane];
  float wc0 = Wc[lane * 2 + 0];
  float wc1 = Wc[lane * 2 + 1];
  float bc0 = bc[0], bc1 = bc[1];
  int gw = blockIdx.x * 4 + wv;
  int nw = gridDim.x * 4;
  int ngroups = (n + 7) >> 3;
  for (int g = gw; g < ngroups; g += nw) {
    int m0 = g * 8;
    lin_stage_inputs(sIn[wv], agg, hin, m0, n, lane);
    float acc[8];
#pragma unroll
    for (int m = 0; m < 8; ++m) acc[m] = bv;
#pragma unroll
    for (int k4 = 0; k4 < 16; ++k4) {
      float wl0 = sWl[(k4 * 4 + 0) * 64 + lane];
      float wl1 = sWl[(k4 * 4 + 1) * 64 + lane];
      float wl2 = sWl[(k4 * 4 + 2) * 64 + lane];
      float wl3 = sWl[(k4 * 4 + 3) * 64 + lane];
      float wr0 = sWr[(k4 * 4 + 0) * 64 + lane];
      float wr1 = sWr[(k4 * 4 + 1) * 64 + lane];
      float wr2 = sWr[(k4 * 4 + 2) * 64 + lane];
      float wr3 = sWr[(k4 * 4 + 3) * 64 + lane];
#pragma unroll
      for (int m = 0; m < 8; ++m) {
        float4 a4 = *(const float4*)&sIn[wv][m][0][k4 * 4];
        float4 x4 = *(const float4*)&sIn[wv][m][1][k4 * 4];
        acc[m] = fmaf(a4.x, wl0, acc[m]);
        acc[m] = fmaf(a4.y, wl1, acc[m]);
        acc[m] = fmaf(a4.z, wl2, acc[m]);
        acc[m] = fmaf(a4.w, wl3, acc[m]);
        acc[m] = fmaf(x4.x, wr0, acc[m]);
        acc[m] = fmaf(x4.y, wr1, acc[m]);
        acc[m] = fmaf(x4.z, wr2, acc[m]);
        acc[m] = fmaf(x4.w, wr3, acc[m]);
      }
    }
    // classifier: per node m, reduce acc[m]*wc over 64 lanes (butterfly)
#pragma unroll
    for (int m = 0; m < 8; ++m) {
      float p0 = acc[m] * wc0;
      float p1 = acc[m] * wc1;
#pragma unroll
      for (int off = 32; off > 0; off >>= 1) {
        p0 += __shfl_xor(p0, off);
        p1 += __shfl_xor(p1, off);
      }
      int row = m0 + m;
      if (lane == 0 && row < n) {
        float2 o;
        o.x = p0 + bc0;
        o.y = p1 + bc1;
        *(float2*)(outp + (size_t)row * 2) = o;
      }
    }
  }
}

extern "C" void kernel_launch(void* const* d_in, const int* in_sizes, int n_in,
                              void* d_out, int out_size, void* d_ws, size_t ws_size,
                              hipStream_t stream) {
  const float* x   = (const float*)d_in[0];
  const int*   ei  = (const int*)d_in[1];
  const float* W1l = (const float*)d_in[2];
  const float* b1  = (const float*)d_in[3];
  const float* W1r = (const float*)d_in[4];
  const float* W2l = (const float*)d_in[5];
  const float* b2  = (const float*)d_in[6];
  const float* W2r = (const float*)d_in[7];
  const float* Wc  = (const float*)d_in[8];
  const float* bc  = (const float*)d_in[9];
  float* out = (float*)d_out;

  const int n  = in_sizes[0] / 64;   // 100000
  const int ne = in_sizes[1] / 2;    // 1600000
  const int* src = ei;
  const int* dst = ei + ne;

  char* ws = (char*)d_ws;
  size_t off = 0;
  auto carve = [&](size_t bytes) -> void* {
    void* p = ws + off;
    off += (bytes + 255) & ~(size_t)255;
    return p;
  };
  const int nb = (n + SCAN_BS - 1) / SCAN_BS;  // 98
  int* deg     = (int*)carve((size_t)n * 4);
  int* row_ptr = (int*)carve((size_t)(n + 1) * 4);
  int* cursor  = (int*)carve((size_t)n * 4);
  int* bsums   = (int*)carve((size_t)(nb + 1) * 4);
  int* boffs   = (int*)carve((size_t)(nb + 1) * 4);
  int* col     = (int*)carve((size_t)ne * 4);
  float* agg   = (float*)carve((size_t)n * 64 * 4);
  float* h     = (float*)carve((size_t)n * 64 * 4);
  (void)ws_size;

  zero_i32_kernel<<<(n + 255) / 256, 256, 0, stream>>>(deg, n);
  hist_kernel<<<(ne + 255) / 256, 256, 0, stream>>>(dst, deg, ne);

  scan_a_kernel<<<nb, SCAN_BS, 0, stream>>>(deg, row_ptr, bsums, n);
  scan_b_kernel<<<1, SCAN_BS, 0, stream>>>(bsums, boffs, nb);
  scan_c_kernel<<<(n + 256) / 256, 256, 0, stream>>>(row_ptr, cursor, boffs, n, nb);

  {
    int W = (n + SCATTER_PASSES - 1) / SCATTER_PASSES;
    for (int p = 0; p < SCATTER_PASSES; ++p) {
      int lo = p * W;
      int hi = (lo + W < n) ? (lo + W) : n;
      scatter_pass_kernel<<<(ne + 255) / 256, 256, 0, stream>>>(src, dst, cursor, col, ne, lo, hi);
    }
  }

  aggregate_kernel<<<(n * 64 + 255) / 256, 256, 0, stream>>>(x, row_ptr, col, agg, n);
  lin_relu_kernel<<<LIN_BLOCKS, 256, 0, stream>>>(agg, x, W1l, b1, W1r, h, n);

  aggregate_kernel<<<(n * 64 + 255) / 256, 256, 0, stream>>>(h, row_ptr, col, agg, n);
  lin2_cls_kernel<<<LIN_BLOCKS, 256, 0, stream>>>(agg, h, W2l, b2, W2r, Wc, bc, out, n);
}

// Round 10
// 530.232 us; speedup vs baseline: 4.1055x; 4.1055x over previous
//
#include <hip/hip_runtime.h>

// ---------------------------------------------------------------------------
// GraphSAGE 2-layer (mean aggr) + linear classifier, fp32, N=100K, D=64, E=16N
// R9: baseline = Round-5's proven 522us config (scan/hist/8-pass scatter/
//  aggregate verbatim). Linears rebuilt as 1-wave blocks, lane = feature j:
//   - weights VGPR-resident (wl[64]/wr[64], constant idx; __launch_bounds__
//     (64,2) gives the 256-VGPR budget so they actually stay in regs;
//     if the compiler demotes, fallback = stride-1 coalesced reloads ~ R2).
//   - node rows via wave-uniform scalar loads (node index from blockIdx/loop
//     only -> s_load_dwordx4), FMA = v_fmac(vacc, s_a, v_w): no LDS, no shfl,
//     8 independent chains per quad. 512 FMA / quad, VALU-dominant.
//  R7/R8 lesson encoded: no pointer arrays, no float4 arrays, no same-wave
//  LDS staging loops the scheduler can hoist into a spill.
// ---------------------------------------------------------------------------

#define SCAN_BS 1024
#define SCATTER_PASSES 8
#define LIN_BLOCKS 2048

__global__ void zero_i32_kernel(int* __restrict__ p, int n) {
  int i = blockIdx.x * blockDim.x + threadIdx.x;
  if (i < n) p[i] = 0;
}

__global__ void hist_kernel(const int* __restrict__ dst, int* __restrict__ deg, int ne) {
  int e = blockIdx.x * blockDim.x + threadIdx.x;
  if (e < ne) atomicAdd(&deg[dst[e]], 1);
}

__device__ __forceinline__ int block_scan_inclusive_1024(int v, int* wsums) {
  int lane = threadIdx.x & 63;
  int wid = threadIdx.x >> 6;
  int s = v;
#pragma unroll
  for (int off = 1; off < 64; off <<= 1) {
    int t = __shfl_up(s, off);
    if (lane >= off) s += t;
  }
  if (lane == 63) wsums[wid] = s;
  __syncthreads();
  if (wid == 0) {
    int ws = (lane < 16) ? wsums[lane] : 0;
#pragma unroll
    for (int off = 1; off < 16; off <<= 1) {
      int t = __shfl_up(ws, off);
      if (lane >= off) ws += t;
    }
    if (lane < 16) wsums[lane] = ws;
  }
  __syncthreads();
  if (wid > 0) s += wsums[wid - 1];
  return s;
}

__global__ void __launch_bounds__(SCAN_BS) scan_a_kernel(const int* __restrict__ deg,
                                                         int* __restrict__ local_excl,
                                                         int* __restrict__ bsums, int n) {
  __shared__ int wsums[16];
  int i = blockIdx.x * SCAN_BS + threadIdx.x;
  int v = (i < n) ? deg[i] : 0;
  int inc = block_scan_inclusive_1024(v, wsums);
  if (i < n) local_excl[i] = inc - v;
  if (threadIdx.x == SCAN_BS - 1) bsums[blockIdx.x] = inc;
}

__global__ void __launch_bounds__(SCAN_BS) scan_b_kernel(const int* __restrict__ bsums,
                                                         int* __restrict__ boffs, int nb) {
  __shared__ int wsums[16];
  int v = ((int)threadIdx.x < nb) ? bsums[threadIdx.x] : 0;
  int inc = block_scan_inclusive_1024(v, wsums);
  if ((int)threadIdx.x < nb) boffs[threadIdx.x] = inc - v;
  if ((int)threadIdx.x == nb - 1) boffs[nb] = inc;
}

__global__ void scan_c_kernel(int* __restrict__ row_ptr, int* __restrict__ cursor,
                              const int* __restrict__ boffs, int n, int nb) {
  int i = blockIdx.x * blockDim.x + threadIdx.x;
  if (i < n) {
    int v = row_ptr[i] + boffs[i >> 10];
    row_ptr[i] = v;
    cursor[i] = v;
  }
  if (i == n) row_ptr[n] = boffs[nb];
}

__global__ void scatter_pass_kernel(const int* __restrict__ src, const int* __restrict__ dst,
                                    int* __restrict__ cursor, int* __restrict__ col,
                                    int ne, int lo, int hi) {
  int e = blockIdx.x * blockDim.x + threadIdx.x;
  if (e < ne) {
    int d = dst[e];
    if (d >= lo && d < hi) {
      int pos = atomicAdd(&cursor[d], 1);
      col[pos] = src[e];
    }
  }
}

// one wave per node, one feature per lane; scalarized col reads, 8 gathers in flight
__global__ void __launch_bounds__(256) aggregate_kernel(const float* __restrict__ xin,
                                                        const int* __restrict__ row_ptr,
                                                        const int* __restrict__ col,
                                                        float* __restrict__ outp, int n) {
  int gwave = (blockIdx.x * 256 + threadIdx.x) >> 6;
  int lane = threadIdx.x & 63;
  if (gwave >= n) return;
  int m = __builtin_amdgcn_readfirstlane(gwave);
  int start = row_ptr[m];
  int end = row_ptr[m + 1];
  float a0 = 0.f, a1 = 0.f, a2 = 0.f, a3 = 0.f, a4 = 0.f, a5 = 0.f, a6 = 0.f, a7 = 0.f;
  int e = start;
  for (; e + 8 <= end; e += 8) {
    int c0 = col[e + 0], c1 = col[e + 1], c2 = col[e + 2], c3 = col[e + 3];
    int c4 = col[e + 4], c5 = col[e + 5], c6 = col[e + 6], c7 = col[e + 7];
    a0 += xin[(size_t)c0 * 64 + lane];
    a1 += xin[(size_t)c1 * 64 + lane];
    a2 += xin[(size_t)c2 * 64 + lane];
    a3 += xin[(size_t)c3 * 64 + lane];
    a4 += xin[(size_t)c4 * 64 + lane];
    a5 += xin[(size_t)c5 * 64 + lane];
    a6 += xin[(size_t)c6 * 64 + lane];
    a7 += xin[(size_t)c7 * 64 + lane];
  }
  for (; e < end; ++e) a0 += xin[(size_t)col[e] * 64 + lane];
  float acc = ((a0 + a1) + (a2 + a3)) + ((a4 + a5) + (a6 + a7));
  int d = end - start;
  float inv = 1.0f / (float)((d > 0) ? d : 1);
  outp[(size_t)m * 64 + lane] = acc * inv;
}

// ---- linear layers: 1-wave blocks, lane = feature, uniform node quads ------

#define LIN_QUAD_BODY(AGG, XIN)                                               \
  float acc0 = bv, acc1 = bv, acc2 = bv, acc3 = bv;                           \
  _Pragma("unroll")                                                           \
  for (int k4 = 0; k4 < 16; ++k4) {                                           \
    float4 a0 = *(const float4*)(AGG + (size_t)(m0 + 0) * 64 + k4 * 4);       \
    float4 a1 = *(const float4*)(AGG + (size_t)(m0 + 1) * 64 + k4 * 4);       \
    float4 a2 = *(const float4*)(AGG + (size_t)(m0 + 2) * 64 + k4 * 4);       \
    float4 a3 = *(const float4*)(AGG + (size_t)(m0 + 3) * 64 + k4 * 4);       \
    float4 x0 = *(const float4*)(XIN + (size_t)(m0 + 0) * 64 + k4 * 4);       \
    float4 x1 = *(const float4*)(XIN + (size_t)(m0 + 1) * 64 + k4 * 4);       \
    float4 x2 = *(const float4*)(XIN + (size_t)(m0 + 2) * 64 + k4 * 4);       \
    float4 x3 = *(const float4*)(XIN + (size_t)(m0 + 3) * 64 + k4 * 4);       \
    _Pragma("unroll")                                                         \
    for (int kk = 0; kk < 4; ++kk) {                                          \
      float wlv = wl[k4 * 4 + kk];                                            \
      float wrv = wr[k4 * 4 + kk];                                            \
      acc0 = fmaf(((const float*)&a0)[kk], wlv, acc0);                        \
      acc1 = fmaf(((const float*)&a1)[kk], wlv, acc1);                        \
      acc2 = fmaf(((const float*)&a2)[kk], wlv, acc2);                        \
      acc3 = fmaf(((const float*)&a3)[kk], wlv, acc3);                        \
      acc0 = fmaf(((const float*)&x0)[kk], wrv, acc0);                        \
      acc1 = fmaf(((const float*)&x1)[kk], wrv, acc1);                        \
      acc2 = fmaf(((const float*)&x2)[kk], wrv, acc2);                        \
      acc3 = fmaf(((const float*)&x3)[kk], wrv, acc3);                        \
    }                                                                         \
  }

__global__ void __launch_bounds__(64, 2) lin_relu_kernel(const float* __restrict__ agg,
                                                         const float* __restrict__ xin,
                                                         const float* __restrict__ Wl,
                                                         const float* __restrict__ bias,
                                                         const float* __restrict__ Wr,
                                                         float* __restrict__ outp, int n) {
  int lane = threadIdx.x;  // 0..63 = output feature j
  float wl[64], wr[64];
#pragma unroll
  for (int k = 0; k < 64; ++k) wl[k] = Wl[k * 64 + lane];
#pragma unroll
  for (int k = 0; k < 64; ++k) wr[k] = Wr[k * 64 + lane];
  float bv = bias[lane];
  int nq = n >> 2;  // n = 100000, divisible by 4
  for (int q = blockIdx.x; q < nq; q += gridDim.x) {
    int m0 = q * 4;  // wave-uniform -> scalar loads below
    LIN_QUAD_BODY(agg, xin)
    outp[(size_t)(m0 + 0) * 64 + lane] = fmaxf(acc0, 0.f);
    outp[(size_t)(m0 + 1) * 64 + lane] = fmaxf(acc1, 0.f);
    outp[(size_t)(m0 + 2) * 64 + lane] = fmaxf(acc2, 0.f);
    outp[(size_t)(m0 + 3) * 64 + lane] = fmaxf(acc3, 0.f);
  }
}

__global__ void __launch_bounds__(64, 2) lin2_cls_kernel(const float* __restrict__ agg,
                                                         const float* __restrict__ hin,
                                                         const float* __restrict__ Wl,
                                                         const float* __restrict__ bias,
                                                         const float* __restrict__ Wr,
                                                         const float* __restrict__ Wc,
                                                         const float* __restrict__ bc,
                                                         float* __restrict__ outp, int n) {
  int lane = threadIdx.x;
  float wl[64], wr[64];
#pragma unroll
  for (int k = 0; k < 64; ++k) wl[k] = Wl[k * 64 + lane];
#pragma unroll
  for (int k = 0; k < 64; ++k) wr[k] = Wr[k * 64 + lane];
  float bv = bias[lane];
  float wc0 = Wc[lane * 2 + 0];
  float wc1 = Wc[lane * 2 + 1];
  float bc0 = bc[0], bc1 = bc[1];
  int nq = n >> 2;
  for (int q = blockIdx.x; q < nq; q += gridDim.x) {
    int m0 = q * 4;
    LIN_QUAD_BODY(agg, hin)
    // classifier: 8 butterfly reductions (4 nodes x 2 logits)
    float p00 = acc0 * wc0, p01 = acc0 * wc1;
    float p10 = acc1 * wc0, p11 = acc1 * wc1;
    float p20 = acc2 * wc0, p21 = acc2 * wc1;
    float p30 = acc3 * wc0, p31 = acc3 * wc1;
#pragma unroll
    for (int off = 32; off > 0; off >>= 1) {
      p00 += __shfl_xor(p00, off); p01 += __shfl_xor(p01, off);
      p10 += __shfl_xor(p10, off); p11 += __shfl_xor(p11, off);
      p20 += __shfl_xor(p20, off); p21 += __shfl_xor(p21, off);
      p30 += __shfl_xor(p30, off); p31 += __shfl_xor(p31, off);
    }
    if (lane < 2) {
      float b2v = (lane == 0) ? bc0 : bc1;
      outp[(size_t)(m0 + 0) * 2 + lane] = ((lane == 0) ? p00 : p01) + b2v;
      outp[(size_t)(m0 + 1) * 2 + lane] = ((lane == 0) ? p10 : p11) + b2v;
      outp[(size_t)(m0 + 2) * 2 + lane] = ((lane == 0) ? p20 : p21) + b2v;
      outp[(size_t)(m0 + 3) * 2 + lane] = ((lane == 0) ? p30 : p31) + b2v;
    }
  }
}

extern "C" void kernel_launch(void* const* d_in, const int* in_sizes, int n_in,
                              void* d_out, int out_size, void* d_ws, size_t ws_size,
                              hipStream_t stream) {
  const float* x   = (const float*)d_in[0];
  const int*   ei  = (const int*)d_in[1];
  const float* W1l = (const float*)d_in[2];
  const float* b1  = (const float*)d_in[3];
  const float* W1r = (const float*)d_in[4];
  const float* W2l = (const float*)d_in[5];
  const float* b2  = (const float*)d_in[6];
  const float* W2r = (const float*)d_in[7];
  const float* Wc  = (const float*)d_in[8];
  const float* bc  = (const float*)d_in[9];
  float* out = (float*)d_out;

  const int n  = in_sizes[0] / 64;   // 100000
  const int ne = in_sizes[1] / 2;    // 1600000
  const int* src = ei;
  const int* dst = ei + ne;

  char* ws = (char*)d_ws;
  size_t off = 0;
  auto carve = [&](size_t bytes) -> void* {
    void* p = ws + off;
    off += (bytes + 255) & ~(size_t)255;
    return p;
  };
  const int nb = (n + SCAN_BS - 1) / SCAN_BS;  // 98
  int* deg     = (int*)carve((size_t)n * 4);
  int* row_ptr = (int*)carve((size_t)(n + 1) * 4);
  int* cursor  = (int*)carve((size_t)n * 4);
  int* bsums   = (int*)carve((size_t)(nb + 1) * 4);
  int* boffs   = (int*)carve((size_t)(nb + 1) * 4);
  int* col     = (int*)carve((size_t)ne * 4);
  float* agg   = (float*)carve((size_t)n * 64 * 4);
  float* h     = (float*)carve((size_t)n * 64 * 4);
  (void)ws_size;

  zero_i32_kernel<<<(n + 255) / 256, 256, 0, stream>>>(deg, n);
  hist_kernel<<<(ne + 255) / 256, 256, 0, stream>>>(dst, deg, ne);

  scan_a_kernel<<<nb, SCAN_BS, 0, stream>>>(deg, row_ptr, bsums, n);
  scan_b_kernel<<<1, SCAN_BS, 0, stream>>>(bsums, boffs, nb);
  scan_c_kernel<<<(n + 256) / 256, 256, 0, stream>>>(row_ptr, cursor, boffs, n, nb);

  {
    int W = (n + SCATTER_PASSES - 1) / SCATTER_PASSES;
    for (int p = 0; p < SCATTER_PASSES; ++p) {
      int lo = p * W;
      int hi = (lo + W < n) ? (lo + W) : n;
      scatter_pass_kernel<<<(ne + 255) / 256, 256, 0, stream>>>(src, dst, cursor, col, ne, lo, hi);
    }
  }

  aggregate_kernel<<<(n * 64 + 255) / 256, 256, 0, stream>>>(x, row_ptr, col, agg, n);
  lin_relu_kernel<<<LIN_BLOCKS, 64, 0, stream>>>(agg, x, W1l, b1, W1r, h, n);

  aggregate_kernel<<<(n * 64 + 255) / 256, 256, 0, stream>>>(h, row_ptr, col, agg, n);
  lin2_cls_kernel<<<LIN_BLOCKS, 64, 0, stream>>>(agg, h, W2l, b2, W2r, Wc, bc, out, n);
}